// Round 8
// baseline (551.684 us; speedup 1.0000x reference)
//
#include <hip/hip_runtime.h>
#include <math.h>

typedef unsigned int u32;
typedef __attribute__((ext_vector_type(8))) short bf16x8;
typedef __attribute__((ext_vector_type(4))) float floatx4;

constexpr int NN = 100000;
constexpr int EE = 1600000;
constexpr int IND = 256;
constexpr int F1 = 32;
constexpr int HF = 128;   // H*F1
constexpr int C  = 40;
constexpr float SLOPE = 0.2f;

constexpr int SCAN_BLOCKS = 100;
constexpr int SCAN_CHUNK  = 1000;   // SCAN_BLOCKS * SCAN_CHUNK == NN

constexpr int SC_NW    = 8;
constexpr int SC_WINW  = (NN + SC_NW - 1) / SC_NW;
constexpr int SC_CHUNK = 8192;
constexpr int SC_NCHUNK = (EE + SC_CHUNK - 1) / SC_CHUNK;

constexpr int H2ROW = 24;  // u32 per h2b row: 20 bf16x2 pairs + el2 bits + pad

__device__ __forceinline__ u32 f2bf(float f) {
    u32 u = __float_as_uint(f);
    return (u + 0x7fffu + ((u >> 16) & 1u)) >> 16;
}
__device__ __forceinline__ float bf_lo(u32 v) { return __uint_as_float(v << 16); }
__device__ __forceinline__ float bf_hi(u32 v) { return __uint_as_float(v & 0xffff0000u); }

// ================= CSR build =================
__global__ __launch_bounds__(256) void k_hist(const int* __restrict__ dst,
                                              int* __restrict__ deg) {
    int e = blockIdx.x * 256 + threadIdx.x;
    if (e < EE) atomicAdd(&deg[dst[e]], 1);
}

__global__ __launch_bounds__(256) void k_scan1(const int* __restrict__ deg,
                                               int* __restrict__ blk_sums) {
    __shared__ int wsum[4];
    const int lane = threadIdx.x & 63, wid = threadIdx.x >> 6;
    const int base = blockIdx.x * SCAN_CHUNK;
    int s = 0;
    for (int i = threadIdx.x; i < SCAN_CHUNK; i += 256) s += deg[base + i];
    #pragma unroll
    for (int m = 1; m < 64; m <<= 1) s += __shfl_xor(s, m, 64);
    if (lane == 0) wsum[wid] = s;
    __syncthreads();
    if (threadIdx.x == 0)
        blk_sums[blockIdx.x] = wsum[0] + wsum[1] + wsum[2] + wsum[3];
}

__global__ __launch_bounds__(128) void k_scan2(int* __restrict__ blk_sums) {
    __shared__ int lds[128];
    const int tid = threadIdx.x;
    int v = (tid < SCAN_BLOCKS) ? blk_sums[tid] : 0;
    lds[tid] = v;
    __syncthreads();
    for (int off = 1; off < 128; off <<= 1) {
        int t = (tid >= off) ? lds[tid - off] : 0;
        __syncthreads();
        lds[tid] += t;
        __syncthreads();
    }
    if (tid < SCAN_BLOCKS) blk_sums[tid] = (tid == 0) ? 0 : lds[tid - 1];
}

__global__ __launch_bounds__(256) void k_scan3(const int* __restrict__ deg,
                                               const int* __restrict__ blk_off,
                                               int* __restrict__ row_ptr,
                                               int* __restrict__ cursor) {
    __shared__ int wsum[4];
    const int tid = threadIdx.x, lane = tid & 63, wid = tid >> 6;
    const int base = blockIdx.x * SCAN_CHUNK;
    const int g0 = tid * 4;
    int v[4];
    #pragma unroll
    for (int i = 0; i < 4; ++i) {
        int gi = g0 + i;
        v[i] = (gi < SCAN_CHUNK) ? deg[base + gi] : 0;
    }
    const int tsum = v[0] + v[1] + v[2] + v[3];
    int s = tsum;
    #pragma unroll
    for (int off = 1; off < 64; off <<= 1) {
        int t = __shfl_up(s, off, 64);
        if (lane >= off) s += t;
    }
    if (lane == 63) wsum[wid] = s;
    __syncthreads();
    int woff = 0;
    for (int w = 0; w < wid; ++w) woff += wsum[w];
    int run = blk_off[blockIdx.x] + woff + (s - tsum);
    #pragma unroll
    for (int i = 0; i < 4; ++i) {
        int gi = g0 + i;
        int idx = base + gi;
        if (gi < SCAN_CHUNK) {
            row_ptr[idx] = run;
            cursor[idx] = run;
            run += v[i];
            if (idx == NN - 1) row_ptr[NN] = run;
        }
    }
}

__global__ __launch_bounds__(256) void k_scatter(const int* __restrict__ src,
                                                 const int* __restrict__ dst,
                                                 int* __restrict__ cursor,
                                                 int* __restrict__ col_src) {
    const int w = blockIdx.x & (SC_NW - 1);
    const int chunk = blockIdx.x >> 3;
    const int lo = w * SC_WINW, hi = lo + SC_WINW;
    const int base = chunk * SC_CHUNK;
    const int lim = min(base + SC_CHUNK, EE);
    for (int i = base + threadIdx.x; i < lim; i += 256) {
        int d = dst[i];
        if (d >= lo && d < hi) {
            int p = atomicAdd(&cursor[d], 1);
            col_src[p] = src[i];
        }
    }
}

// ================= prep: w1t_g[n][kpair] = bf16x2 of W1^T (64 KB, L2-resident) =======
__global__ __launch_bounds__(256) void k_prep(const float* __restrict__ W1,
                                              u32* __restrict__ w1t_g) {
    const int idx = blockIdx.x * 256 + threadIdx.x;  // 16384 total
    const int kp = idx >> 7, n = idx & 127;
    const float f0 = W1[(size_t)(kp * 2) * HF + n];
    const float f1 = W1[(size_t)(kp * 2 + 1) * HF + n];
    w1t_g[n * 128 + kp] = (f2bf(f1) << 16) | f2bf(f0);
}

// ================= GEMM1 (MFMA bf16, LDS-free): h1b = bf16(feat @ W1), + el1/er1 =====
// B-frags load straight from L2-resident w1t_g; no LDS, no staging, no syncthreads.
__global__ __launch_bounds__(256) void k_gemm1(const float* __restrict__ feat,
                                               const u32* __restrict__ w1t_g,
                                               const float* __restrict__ al1,
                                               const float* __restrict__ ar1,
                                               u32* __restrict__ h1b,
                                               float* __restrict__ el1,
                                               float* __restrict__ er1) {
    const int tid = threadIdx.x;
    const int w = tid >> 6, lane = tid & 63;
    const int quad = lane >> 4, l15 = lane & 15;
    const int rbase = blockIdx.x * 128 + w * 32;

    float alv[4][2], arv[4][2];
    #pragma unroll
    for (int h = 0; h < 4; ++h) {
        alv[h][0] = al1[h * F1 + l15];
        alv[h][1] = al1[h * F1 + 16 + l15];
        arv[h][0] = ar1[h * F1 + l15];
        arv[h][1] = ar1[h * F1 + 16 + l15];
    }

    floatx4 acc[2][8] = {};
    for (int ks = 0; ks < 8; ++ks) {
        bf16x8 a[2];
        #pragma unroll
        for (int ri = 0; ri < 2; ++ri) {
            int row = rbase + ri * 16 + l15;
            row = row < NN ? row : NN - 1;
            const size_t base = (size_t)row * IND + ks * 32 + quad * 8;
            const float4 f0 = *(const float4*)&feat[base];
            const float4 f1 = *(const float4*)&feat[base + 4];
            uint4 p;
            p.x = (f2bf(f0.y) << 16) | f2bf(f0.x);
            p.y = (f2bf(f0.w) << 16) | f2bf(f0.z);
            p.z = (f2bf(f1.y) << 16) | f2bf(f1.x);
            p.w = (f2bf(f1.w) << 16) | f2bf(f1.z);
            a[ri] = *(bf16x8*)&p;
        }
        const int g = ks * 4 + quad;
        #pragma unroll
        for (int ci = 0; ci < 8; ++ci) {
            const uint4 bw = *(const uint4*)&w1t_g[(ci * 16 + l15) * 128 + g * 4];
            bf16x8 b = *(bf16x8*)&bw;
            acc[0][ci] = __builtin_amdgcn_mfma_f32_16x16x32_bf16(a[0], b, acc[0][ci], 0, 0, 0);
            acc[1][ci] = __builtin_amdgcn_mfma_f32_16x16x32_bf16(a[1], b, acc[1][ci], 0, 0, 0);
        }
    }

    // ---- epilogue: pack h1b + compute el1/er1 from f32 acc ----
    #pragma unroll
    for (int ri = 0; ri < 2; ++ri) {
        #pragma unroll
        for (int r = 0; r < 4; ++r) {
            const int row = rbase + ri * 16 + quad * 4 + r;
            const bool rok = row < NN;
            #pragma unroll
            for (int h = 0; h < 4; ++h) {
                float pe = acc[ri][2 * h][r] * alv[h][0] + acc[ri][2 * h + 1][r] * alv[h][1];
                float pr = acc[ri][2 * h][r] * arv[h][0] + acc[ri][2 * h + 1][r] * arv[h][1];
                #pragma unroll
                for (int m = 1; m < 16; m <<= 1) {
                    pe += __shfl_xor(pe, m, 64);
                    pr += __shfl_xor(pr, m, 64);
                }
                if (l15 == 0 && rok) {
                    el1[row * 4 + h] = pe;
                    er1[row * 4 + h] = pr;
                }
            }
            #pragma unroll
            for (int ci = 0; ci < 8; ++ci) {
                float v = acc[ri][ci][r];
                float vn = __shfl_xor(v, 1, 64);
                if (!(lane & 1) && rok) {
                    h1b[(size_t)row * 64 + ci * 8 + (l15 >> 1)] =
                        (f2bf(vn) << 16) | f2bf(v);
                }
            }
        }
    }
}

// ================= layer-1 aggregation: wave per dst, 4-edge ILP, bf16 x out =========
__global__ __launch_bounds__(256) void k_agg1(const int* __restrict__ row_ptr,
                                              const int* __restrict__ col_src,
                                              const u32* __restrict__ h1b,
                                              const float* __restrict__ el1,
                                              const float* __restrict__ er1,
                                              const float* __restrict__ b1,
                                              u32* __restrict__ x_b) {
    const int wid = threadIdx.x >> 6, lane = threadIdx.x & 63;
    const int d = blockIdx.x * 4 + wid;
    if (d >= NN) return;
    const int head = lane >> 4;
    const float erd = er1[d * 4 + head];
    const int beg = row_ptr[d], end = row_ptr[d + 1];
    float accx = 0.f, accy = 0.f, ssum = 0.f;
    int e = beg;
    for (; e + 4 <= end; e += 4) {
        const int s0 = col_src[e],     s1 = col_src[e + 1];
        const int s2 = col_src[e + 2], s3 = col_src[e + 3];
        const u32 v0 = h1b[(size_t)s0 * 64 + lane];
        const u32 v1 = h1b[(size_t)s1 * 64 + lane];
        const u32 v2 = h1b[(size_t)s2 * 64 + lane];
        const u32 v3 = h1b[(size_t)s3 * 64 + lane];
        float c0 = el1[s0 * 4 + head] + erd;
        float c1 = el1[s1 * 4 + head] + erd;
        float c2 = el1[s2 * 4 + head] + erd;
        float c3 = el1[s3 * 4 + head] + erd;
        c0 = c0 > 0.f ? c0 : SLOPE * c0;
        c1 = c1 > 0.f ? c1 : SLOPE * c1;
        c2 = c2 > 0.f ? c2 : SLOPE * c2;
        c3 = c3 > 0.f ? c3 : SLOPE * c3;
        const float e0 = __expf(c0), e1 = __expf(c1);
        const float e2 = __expf(c2), e3 = __expf(c3);
        ssum += (e0 + e1) + (e2 + e3);
        accx += e0 * bf_lo(v0) + e1 * bf_lo(v1) + e2 * bf_lo(v2) + e3 * bf_lo(v3);
        accy += e0 * bf_hi(v0) + e1 * bf_hi(v1) + e2 * bf_hi(v2) + e3 * bf_hi(v3);
    }
    for (; e < end; ++e) {
        const int s = col_src[e];
        const u32 v = h1b[(size_t)s * 64 + lane];
        float c = el1[s * 4 + head] + erd;
        c = c > 0.f ? c : SLOPE * c;
        const float ee = __expf(c);
        ssum += ee;
        accx += ee * bf_lo(v);
        accy += ee * bf_hi(v);
    }
    const float inv = ssum > 0.f ? 1.f / ssum : 0.f;
    const float2 b = *(const float2*)&b1[lane * 2];
    float rx = accx * inv + b.x;
    float ry = accy * inv + b.y;
    rx = rx > 0.f ? rx : expm1f(rx);
    ry = ry > 0.f ? ry : expm1f(ry);
    x_b[(size_t)d * 64 + lane] = (f2bf(ry) << 16) | f2bf(rx);
}

// ================= GEMM2 (MFMA bf16): h2b = pack(x @ [W2|waux_l|waux_r]) =============
__global__ __launch_bounds__(256) void k_gemm2(const u32* __restrict__ x_b,
                                               const float* __restrict__ W2,
                                               const float* __restrict__ al2,
                                               const float* __restrict__ ar2,
                                               u32* __restrict__ h2b,
                                               float* __restrict__ er2) {
    __shared__ u32 w2t[48 * 64];
    const int tid = threadIdx.x;
    {
        const int o = tid & 15;
        const int n0 = tid >> 4;
        for (int n = n0; n < 48; n += 16) {
            float f[8];
            #pragma unroll
            for (int j = 0; j < 8; ++j) {
                const int k = o * 8 + j;
                float v;
                if (n < C) v = W2[(size_t)k * C + n];
                else if (n == 40) {
                    v = 0.f;
                    for (int c = 0; c < C; ++c) v += W2[(size_t)k * C + c] * al2[c];
                } else if (n == 41) {
                    v = 0.f;
                    for (int c = 0; c < C; ++c) v += W2[(size_t)k * C + c] * ar2[c];
                } else v = 0.f;
                f[j] = v;
            }
            uint4 p;
            p.x = (f2bf(f[1]) << 16) | f2bf(f[0]);
            p.y = (f2bf(f[3]) << 16) | f2bf(f[2]);
            p.z = (f2bf(f[5]) << 16) | f2bf(f[4]);
            p.w = (f2bf(f[7]) << 16) | f2bf(f[6]);
            *(uint4*)&w2t[n * 64 + ((o ^ (n & 7)) << 2)] = p;
        }
    }
    __syncthreads();

    const int w = tid >> 6, lane = tid & 63;
    const int quad = lane >> 4, l15 = lane & 15;
    const int rbase = blockIdx.x * 128 + w * 32;
    floatx4 acc[2][3] = {};

    #pragma unroll
    for (int ks = 0; ks < 4; ++ks) {
        bf16x8 a[2];
        #pragma unroll
        for (int ri = 0; ri < 2; ++ri) {
            int row = rbase + ri * 16 + l15;
            row = row < NN ? row : NN - 1;
            uint4 ax = *(const uint4*)&x_b[(size_t)row * 64 + ks * 16 + quad * 4];
            a[ri] = *(bf16x8*)&ax;
        }
        const int g = ks * 4 + quad;
        #pragma unroll
        for (int ci = 0; ci < 3; ++ci) {
            const int n = ci * 16 + l15;
            uint4 bw = *(const uint4*)&w2t[n * 64 + ((g ^ (n & 7)) << 2)];
            bf16x8 b = *(bf16x8*)&bw;
            acc[0][ci] = __builtin_amdgcn_mfma_f32_16x16x32_bf16(a[0], b, acc[0][ci], 0, 0, 0);
            acc[1][ci] = __builtin_amdgcn_mfma_f32_16x16x32_bf16(a[1], b, acc[1][ci], 0, 0, 0);
        }
    }

    #pragma unroll
    for (int ri = 0; ri < 2; ++ri) {
        #pragma unroll
        for (int r = 0; r < 4; ++r) {
            const int row = rbase + ri * 16 + quad * 4 + r;
            const bool rok = row < NN;
            #pragma unroll
            for (int ci = 0; ci < 3; ++ci) {
                float v = acc[ri][ci][r];
                float vn = __shfl_xor(v, 1, 64);
                if (rok) {
                    if (ci < 2) {
                        if (!(lane & 1))
                            h2b[(size_t)row * H2ROW + ci * 8 + (l15 >> 1)] =
                                (f2bf(vn) << 16) | f2bf(v);
                    } else {
                        if (!(lane & 1) && l15 < 8)
                            h2b[(size_t)row * H2ROW + 16 + (l15 >> 1)] =
                                (f2bf(vn) << 16) | f2bf(v);
                        else if (l15 == 8)
                            h2b[(size_t)row * H2ROW + 20] = __float_as_uint(v);
                        else if (l15 == 9)
                            er2[row] = v;
                    }
                }
            }
        }
    }
}

// ================= layer-2 aggregation =================
__global__ __launch_bounds__(256) void k_agg2(const int* __restrict__ row_ptr,
                                              const int* __restrict__ col_src,
                                              const u32* __restrict__ h2b,
                                              const float* __restrict__ er2,
                                              const float* __restrict__ b2,
                                              float* __restrict__ out) {
    const int wid = threadIdx.x >> 6, lane = threadIdx.x & 63;
    const int d = blockIdx.x * 4 + wid;
    if (d >= NN) return;
    const float erd = er2[d];
    const int beg = row_ptr[d], end = row_ptr[d + 1];
    const bool act = lane < 20;
    const int ld = act ? lane : 20;
    float acc0 = 0.f, acc1 = 0.f, ssum = 0.f;
    int e = beg;
    for (; e + 4 <= end; e += 4) {
        const int s0 = col_src[e],     s1 = col_src[e + 1];
        const int s2 = col_src[e + 2], s3 = col_src[e + 3];
        const u32 v0 = h2b[(size_t)s0 * H2ROW + ld];
        const u32 v1 = h2b[(size_t)s1 * H2ROW + ld];
        const u32 v2 = h2b[(size_t)s2 * H2ROW + ld];
        const u32 v3 = h2b[(size_t)s3 * H2ROW + ld];
        float c0 = __uint_as_float(h2b[(size_t)s0 * H2ROW + 20]) + erd;
        float c1 = __uint_as_float(h2b[(size_t)s1 * H2ROW + 20]) + erd;
        float c2 = __uint_as_float(h2b[(size_t)s2 * H2ROW + 20]) + erd;
        float c3 = __uint_as_float(h2b[(size_t)s3 * H2ROW + 20]) + erd;
        c0 = c0 > 0.f ? c0 : SLOPE * c0;
        c1 = c1 > 0.f ? c1 : SLOPE * c1;
        c2 = c2 > 0.f ? c2 : SLOPE * c2;
        c3 = c3 > 0.f ? c3 : SLOPE * c3;
        const float e0 = __expf(c0), e1 = __expf(c1);
        const float e2 = __expf(c2), e3 = __expf(c3);
        ssum += (e0 + e1) + (e2 + e3);
        acc0 += e0 * bf_lo(v0) + e1 * bf_lo(v1) + e2 * bf_lo(v2) + e3 * bf_lo(v3);
        acc1 += e0 * bf_hi(v0) + e1 * bf_hi(v1) + e2 * bf_hi(v2) + e3 * bf_hi(v3);
    }
    for (; e < end; ++e) {
        const int s = col_src[e];
        const u32 v = h2b[(size_t)s * H2ROW + ld];
        float c = __uint_as_float(h2b[(size_t)s * H2ROW + 20]) + erd;
        c = c > 0.f ? c : SLOPE * c;
        const float ee = __expf(c);
        ssum += ee;
        acc0 += ee * bf_lo(v);
        acc1 += ee * bf_hi(v);
    }
    if (act) {
        const float inv = ssum > 0.f ? 1.f / ssum : 0.f;
        const float2 b = *(const float2*)&b2[lane * 2];
        float2 r;
        r.x = acc0 * inv + b.x;
        r.y = acc1 * inv + b.y;
        *(float2*)&out[(size_t)d * C + lane * 2] = r;
    }
}

extern "C" void kernel_launch(void* const* d_in, const int* in_sizes, int n_in,
                              void* d_out, int out_size, void* d_ws, size_t ws_size,
                              hipStream_t stream) {
    const float* feat = (const float*)d_in[0];
    const int*   src  = (const int*)d_in[1];
    const int*   dst  = (const int*)d_in[2];
    const float* W1   = (const float*)d_in[3];
    const float* al1  = (const float*)d_in[4];
    const float* ar1  = (const float*)d_in[5];
    const float* b1   = (const float*)d_in[6];
    const float* W2   = (const float*)d_in[7];
    const float* al2  = (const float*)d_in[8];
    const float* ar2  = (const float*)d_in[9];
    const float* b2   = (const float*)d_in[10];
    float* out = (float*)d_out;

    // ---- workspace layout ----
    u32*   h1b = (u32*)d_ws;                        // N*64 u32; reused as h2b (N*24)
    u32*   x_b = h1b + (size_t)NN * 64;             // N*64 u32 (bf16 x)
    float* el1 = (float*)(x_b + (size_t)NN * 64);   // N*4
    float* er1 = el1 + (size_t)NN * 4;              // N*4 (er2 reuses: N)
    int* row_ptr = (int*)(er1 + (size_t)NN * 4);    // N+1
    int* cursor  = row_ptr + (NN + 1);              // N
    int* deg     = cursor + NN;                     // N
    int* blk_sums = deg + NN;                       // SCAN_BLOCKS
    int* col_src = blk_sums + SCAN_BLOCKS;          // E
    u32* w1t_g   = (u32*)(col_src + EE);            // 128*128 u32 (64 KB)
    u32*   h2b = h1b;
    float* er2 = er1;

    // ---- CSR build + weight prep ----
    hipMemsetAsync(deg, 0, (size_t)NN * sizeof(int), stream);
    k_hist<<<(EE + 255) / 256, 256, 0, stream>>>(dst, deg);
    k_prep<<<64, 256, 0, stream>>>(W1, w1t_g);
    k_scan1<<<SCAN_BLOCKS, 256, 0, stream>>>(deg, blk_sums);
    k_scan2<<<1, 128, 0, stream>>>(blk_sums);
    k_scan3<<<SCAN_BLOCKS, 256, 0, stream>>>(deg, blk_sums, row_ptr, cursor);
    k_scatter<<<SC_NCHUNK * SC_NW, 256, 0, stream>>>(src, dst, cursor, col_src);

    // ---- layer 1 ----
    k_gemm1<<<(NN + 127) / 128, 256, 0, stream>>>(feat, w1t_g, al1, ar1, h1b, el1, er1);
    k_agg1<<<NN / 4, 256, 0, stream>>>(row_ptr, col_src, h1b, el1, er1, b1, x_b);

    // ---- layer 2 ----
    k_gemm2<<<(NN + 127) / 128, 256, 0, stream>>>(x_b, W2, al2, ar2, h2b, er2);
    k_agg2<<<NN / 4, 256, 0, stream>>>(row_ptr, col_src, h2b, er2, b2, out);
}